// Round 12
// baseline (212.880 us; speedup 1.0000x reference)
//
#include <hip/hip_runtime.h>
#include <hip/hip_bf16.h>

// SpatioTemporalLayer: N=8,C=256,T=120,V=25,W=5,PAD=2,H=8,CO=256,HD=32,L=125
// Round 22: INSTRUMENTATION round. k_attn split into 3 equal dispatches
//   (2560 blocks = exactly 2.0 residency rounds each, ~19us apiece) so the
//   rocprof top-5 window can expose any non-attn kernel in the 19-56us range
//   (prep/G1/ffn have been invisible behind attn's 56us instances; their
//   modeled sum ~30us vs measured ~150us non-attn budget is unreconciled).
//   If nothing surfaces: all < 19us -> gaps dominate -> next round fuses
//   kernels. Everything else identical to R21 (best: 206.0us).
//  P : k_prep | G1: k_gemm<0> (XCD-swizzled) | A : k_attn x3 | F : k_ffn

using bf16  = __bf16;
using bf16x8 = __bf16 __attribute__((ext_vector_type(8)));
using f32x4  = float __attribute__((ext_vector_type(4)));
using f32x16 = float __attribute__((ext_vector_type(16)));
using uint32x4 = unsigned int __attribute__((ext_vector_type(4)));

#define GAS __attribute__((address_space(1)))
#define LAS __attribute__((address_space(3)))

__device__ __forceinline__ void gload_lds16(const void* g, void* l) {
  __builtin_amdgcn_global_load_lds((GAS void*)g, (LAS void*)l, 16, 0, 0);
}

__device__ __forceinline__ unsigned cvt_pk_bf16(float lo, float hi) {
  unsigned r;
  asm("v_cvt_pk_bf16_f32 %0, %1, %2" : "=v"(r) : "v"(lo), "v"(hi));
  return r;
}

__device__ __forceinline__ void pl32_swap(unsigned& a, unsigned& b) {
  asm("v_permlane32_swap_b32 %0, %1" : "+v"(a), "+v"(b));
}

// ---------------- diagnostic fallback ----------------
__global__ void k_zero(float* out, int n) {
  int i = blockIdx.x * 256 + threadIdx.x;
  if (i < n) out[i] = 0.f;
}

// ---------------- P: merged prep (x-transpose | weights | pad zero) --------
__global__ void k_prep(const float* __restrict__ x,
                       const float* __restrict__ wqkv, const float* __restrict__ wout,
                       const float* __restrict__ b_out,
                       const float* __restrict__ w1, const float* __restrict__ w2,
                       const float* __restrict__ g1, const float* __restrict__ b1,
                       const float* __restrict__ m1, const float* __restrict__ v1,
                       const float* __restrict__ gf, const float* __restrict__ bff,
                       const float* __restrict__ mf, const float* __restrict__ vf,
                       const float* __restrict__ g2, const float* __restrict__ b2,
                       const float* __restrict__ m2, const float* __restrict__ v2,
                       bf16* __restrict__ Xrow, bf16* __restrict__ WqT,
                       bf16* __restrict__ WoT, bf16* __restrict__ W1c,
                       bf16* __restrict__ W2c, float* __restrict__ pb) {
  __shared__ bf16 T[64 * 72];              // pitch 72 breaks transpose conflicts
  const int b = blockIdx.x, tid = threadIdx.x;
  if (b < 1504) {                          // ---- x transpose tile ----
    const int bx = b % 47, by = (b / 47) & 3, n = b / 188;
    const int tv0 = bx * 64, c0 = by * 64;
    const int la = tid & 63, sub = tid >> 6;
#pragma unroll 4
    for (int i = 0; i < 16; ++i) {
      int c = c0 + sub + i * 4;
      int tv = tv0 + la;
      float v = (tv < 3000) ? x[(size_t)(n * 256 + c) * 3000 + tv] : 0.f;
      T[(sub + i * 4) * 72 + la] = (bf16)v;
    }
    __syncthreads();
#pragma unroll 4
    for (int i = 0; i < 16; ++i) {
      int tvl = sub + i * 4;
      int tv = tv0 + tvl;
      if (tv < 3000)
        Xrow[(size_t)(n * 3100 + 50 + tv) * 256 + c0 + la] = T[la * 72 + tvl];
    }
  } else if (b < 3041) {                   // ---- weights + BN params ----
    int idx = (b - 1504) * 256 + tid;
    if (idx < 196608) {
      int c = idx / 768, o = idx % 768;
      float vv = wqkv[idx];
      if ((o % 96) < 32) vv *= 0.0901387929f;   // fold (1/16)*log2e into Wq
      WqT[o * 256 + c] = (bf16)vv;
    } else if (idx < 262144) {
      int j = idx - 196608;
      int c = j >> 8, o = j & 255;
      WoT[o * 256 + c] = (bf16)wout[j];
    } else if (idx < 327680) {
      int j = idx - 262144;
      W1c[j] = (bf16)w1[j];
    } else if (idx < 393216) {
      int j = idx - 327680;
      W2c[j] = (bf16)w2[j];
    } else if (idx < 393472) {
      int k = idx - 393216;
      float s1 = g1[k] * rsqrtf(v1[k] + 1e-5f);
      pb[k]        = s1;
      pb[256 + k]  = b1[k] - m1[k] * s1;
      float sf = gf[k] * rsqrtf(vf[k] + 1e-5f);
      pb[512 + k]  = sf;
      pb[768 + k]  = bff[k] - mf[k] * sf;
      float s2 = g2[k] * rsqrtf(v2[k] + 1e-5f);
      pb[1024 + k] = s2;
      pb[1280 + k] = b2[k] - m2[k] * s2;
      pb[1536 + k] = b_out[k];
    }
  } else {                                 // ---- zero t-pad rows of Xrow ----
    int z = b - 3041;                      // 0..99
    int idx16 = z * 256 + tid;             // each writes 8 bf16 (16 B)
    int e0 = idx16 * 8;
    int pr = e0 >> 8, col = e0 & 255;      // pad row 0..799
    int n = pr / 100, r100 = pr % 100;
    int row = n * 3100 + (r100 < 50 ? r100 : 3000 + r100);
    int4 zz = {};
    *(int4*)&Xrow[(size_t)row * 256 + col] = zz;
  }
}

// ---------------- GEMM (2-phase dbuf, global_load_lds w16, 3/CU) ----------
// EPI==0 applies the bijective XCD swizzle (nwg=1164 -> q=145, r=4).
template <int EPI>
__global__ __launch_bounds__(256, 3) void k_gemm(
    const bf16* __restrict__ A, const bf16* __restrict__ BT,
    bf16* __restrict__ Cout, int ldc, int Mreal,
    const float* __restrict__ pb, const bf16* __restrict__ Res,
    float* __restrict__ Out2) {
  __shared__ __align__(16) char smem[32768];   // 2 x (As 8K | Bs 8K); Tt overlay
  const int tid = threadIdx.x;
  const int w = tid >> 6, lane = tid & 63, q = lane >> 4, l15 = lane & 15;
  int bx = blockIdx.x, by = blockIdx.y;
  if constexpr (EPI == 0) {
    int orig = bx + by * 194;              // gridDim = (194, 6), x-fastest
    int xcd = orig & 7, j = orig >> 3;     // round-robin XCD assignment
    int swz = (xcd < 4) ? xcd * 146 + j : 584 + (xcd - 4) * 145 + j;
    bx = swz / 6; by = swz % 6;            // contiguous m-chunk per XCD
  }
  const int m0 = bx * 128, n0 = by * 128;
  const int wm = (w >> 1) * 64, wn = (w & 1) * 64;
  const int srow = tid >> 2;            // 0..63
  const int scol = (tid & 3) << 3;
  int ar1 = m0 + srow;        if (ar1 >= Mreal) ar1 = Mreal - 1;
  int ar2 = m0 + srow + 64;   if (ar2 >= Mreal) ar2 = Mreal - 1;
  const bf16* gA1 = A  + (size_t)ar1 * 256 + scol;
  const bf16* gA2 = A  + (size_t)ar2 * 256 + scol;
  const bf16* gB1 = BT + (size_t)(n0 + srow) * 256 + scol;
  const bf16* gB2 = gB1 + 64 * 256;
  f32x4 acc[4][4] = {};

  auto STAGE = [&](int ks, char* buf) {
    char* ldsA = buf + w * 1024;          // lane-linear dest per wave
    char* ldsB = buf + 8192 + w * 1024;
    gload_lds16(gA1 + ks * 32, ldsA);
    gload_lds16(gA2 + ks * 32, ldsA + 4096);
    gload_lds16(gB1 + ks * 32, ldsB);
    gload_lds16(gB2 + ks * 32, ldsB + 4096);
  };

  int cur = 0;
  STAGE(0, smem);
  __syncthreads();
  for (int ks = 0; ks < 8; ++ks) {
    if (ks < 7) STAGE(ks + 1, smem + ((cur ^ 1) << 14));
    const bf16* Asc = (const bf16*)(smem + (cur << 14));
    const bf16* Bsc = Asc + 4096;         // +8192 bytes
    bf16x8 af[4], bfr[4];
#pragma unroll
    for (int i = 0; i < 4; ++i) af[i]  = *(const bf16x8*)&Asc[(wm + i * 16 + l15) * 32 + q * 8];
#pragma unroll
    for (int i = 0; i < 4; ++i) bfr[i] = *(const bf16x8*)&Bsc[(wn + i * 16 + l15) * 32 + q * 8];
#pragma unroll
    for (int i = 0; i < 4; ++i)
#pragma unroll
      for (int j = 0; j < 4; ++j)
        acc[i][j] = __builtin_amdgcn_mfma_f32_16x16x32_bf16(af[i], bfr[j], acc[i][j], 0, 0, 0);
    __syncthreads();
    cur ^= 1;
  }

  if constexpr (EPI != 3) {
#pragma unroll
    for (int i = 0; i < 4; ++i) {
#pragma unroll
      for (int j = 0; j < 4; ++j) {
#pragma unroll
        for (int r = 0; r < 4; ++r) {
          int row = m0 + wm + i * 16 + q * 4 + r;
          int col = n0 + wn + j * 16 + l15;
          if (row >= Mreal) continue;
          float v = acc[i][j][r];
          if constexpr (EPI == 0) {
            Cout[(size_t)row * ldc + col] = (bf16)v;
          } else if constexpr (EPI == 1) {
            v += pb[1536 + col];                       // b_out
            int n = row / 3000;                       // x residual at Xrow row+n*100+50
            v += (float)Res[(size_t)(row + n * 100 + 50) * 256 + col];
            v = v * pb[col] + pb[256 + col];          // BN1
            Cout[(size_t)row * 256 + col] = (bf16)v;
          } else {                                    // EPI == 2
            float ex = __expf(v);                     // mish
            float a = 1.f + ex;
            float u = 1.f / (a * a);
            v = v * (1.f - u) / (1.f + u);
            v = v * pb[512 + col] + pb[768 + col];    // BN ffn
            Cout[(size_t)row * 256 + col] = (bf16)v;
          }
        }
      }
    }
  } else {
    // EPI3: +interR residual, BN2, LDS-transposed coalesced fp32 store
    float* Tt = (float*)smem;              // 2 tiles of 128 x pitch-19 fp32
    const int tti = (w & 1);               // wave's col-half
#pragma unroll
    for (int jj = 0; jj < 4; ++jj) {
      __syncthreads();                     // previous phase's Tt reads done
#pragma unroll
      for (int i = 0; i < 4; ++i) {
#pragma unroll
        for (int r = 0; r < 4; ++r) {
          int rowl = wm + i * 16 + q * 4 + r;
          int row = m0 + rowl;
          int col = n0 + tti * 64 + jj * 16 + l15;
          float v = acc[i][jj][r];
          v += (float)Res[(size_t)row * 256 + col];   // + interR (in-bounds alloc)
          v = v * pb[1024 + col] + pb[1280 + col];    // BN2
          Tt[tti * 2432 + rowl * 19 + l15] = v;
        }
      }
      __syncthreads();
#pragma unroll
      for (int k = 0; k < 16; ++k) {
        int flat = k * 256 + tid;          // 4096 values
        int tt2 = flat >> 11;
        int rem = flat & 2047;
        int colL = rem >> 7;
        int rowl = rem & 127;
        int row = m0 + rowl;
        if (row < Mreal) {
          int col = n0 + tt2 * 64 + jj * 16 + colL;
          int n = row / 3000, r2 = row - n * 3000;
          Out2[(size_t)(n * 256 + col) * 3000 + r2] = Tt[tt2 * 2432 + rowl * 19 + colL];
        }
      }
    }
  }
}

// ---------------- F: fused FFN chain (G2+G3+G4), 32-row tiles, 3/CU -------
__global__ __launch_bounds__(256, 3) void k_ffn(
    const bf16* __restrict__ Aom, const bf16* __restrict__ Wo,
    const bf16* __restrict__ W1, const bf16* __restrict__ W2,
    const bf16* __restrict__ Xres, const float* __restrict__ pb,
    float* __restrict__ Out2) {
  __shared__ __align__(16) char smem[53760];
  // As dbuf [2][32][32] @ 0,2048 ; Bs dbuf [2][256][32] @ 4096,20480
  // XI [32][264] @ 36864 ; Tt overlay [32][65] f32 @ 0
  bf16* XI = (bf16*)(smem + 36864);
  float* Tt = (float*)smem;
  const int tid = threadIdx.x;
  const int w = tid >> 6, lane = tid & 63, q = lane >> 4, l15 = lane & 15;
  const int r0 = blockIdx.x * 32;
  const int srow = tid >> 2, scol = (tid & 3) << 3;

  auto STAGE_A = [&](int ks, int b) {
    if (w == 0) {                          // 2 KB: wave 0 issues 2 gloads
      char* ldsA = smem + (b << 11);
      const bf16* src = Aom + (size_t)(r0 + (lane >> 2)) * 256 + ks * 32 + ((lane & 3) << 3);
      gload_lds16(src, ldsA);              // rows 0..15
      gload_lds16(src + 16 * 256, ldsA + 1024);  // rows 16..31
    }
  };
  auto STAGE_B = [&](const bf16* Wsrc, int ks, int b) {
    char* ldsB = smem + 4096 + (b << 14) + w * 1024;
#pragma unroll
    for (int ii = 0; ii < 4; ++ii)
      gload_lds16(Wsrc + (size_t)(ii * 64 + srow) * 256 + ks * 32 + scol,
                  ldsB + ii * 4096);
  };

  f32x4 acc[2][4];
#pragma unroll
  for (int i = 0; i < 2; ++i)
#pragma unroll
    for (int j = 0; j < 4; ++j) acc[i][j] = f32x4{};

  // ================= phase 1: om @ Wo =================
  int cur = 0;
  STAGE_A(0, 0); STAGE_B(Wo, 0, 0);
  __syncthreads();
  for (int ks = 0; ks < 8; ++ks) {
    if (ks < 7) { STAGE_A(ks + 1, cur ^ 1); STAGE_B(Wo, ks + 1, cur ^ 1); }
    const bf16* Asc = (const bf16*)(smem + (cur << 11));
    const bf16* Bsc = (const bf16*)(smem + 4096 + (cur << 14));
    bf16x8 af[2], bfr[4];
#pragma unroll
    for (int i = 0; i < 2; ++i) af[i]  = *(const bf16x8*)&Asc[(i * 16 + l15) * 32 + q * 8];
#pragma unroll
    for (int j = 0; j < 4; ++j) bfr[j] = *(const bf16x8*)&Bsc[(w * 64 + j * 16 + l15) * 32 + q * 8];
#pragma unroll
    for (int i = 0; i < 2; ++i)
#pragma unroll
      for (int j = 0; j < 4; ++j)
        acc[i][j] = __builtin_amdgcn_mfma_f32_16x16x32_bf16(af[i], bfr[j], acc[i][j], 0, 0, 0);
    __syncthreads();
    cur ^= 1;
  }
  // pre-issue phase-2's first weight stage; hide under epilogue 1
  STAGE_B(W1, 0, 0);
  // epilogue 1: +b_out, +x residual, BN1 -> XI (LDS) + irk (packed regs)
  unsigned irk[16];
#pragma unroll
  for (int i = 0; i < 2; ++i) {
#pragma unroll
    for (int j = 0; j < 4; ++j) {
      int colb = w * 64 + j * 16 + l15;
      float vv[4];
#pragma unroll
      for (int r = 0; r < 4; ++r) {
        int grow = r0 + i * 16 + q * 4 + r;
        int nn = grow / 3000;
        float v = acc[i][j][r] + pb[1536 + colb]
                + (float)Xres[(size_t)(grow + nn * 100 + 50) * 256 + colb];
        v = v * pb[colb] + pb[256 + colb];
        vv[r] = v;
        XI[(i * 16 + q * 4 + r) * 264 + colb] = (bf16)v;
      }
      irk[(i * 4 + j) * 2 + 0] = cvt_pk_bf16(vv[0], vv[1]);
      irk[(i * 4 + j) * 2 + 1] = cvt_pk_bf16(vv[2], vv[3]);
    }
  }
  __syncthreads();                        // XI + staged W1(ks=0) ready

  // ================= phase 2: interR @ W1^T, mish, BNf =================
#pragma unroll
  for (int i = 0; i < 2; ++i)
#pragma unroll
    for (int j = 0; j < 4; ++j) acc[i][j] = f32x4{};
  cur = 0;
  for (int ks = 0; ks < 8; ++ks) {
    if (ks < 7) STAGE_B(W1, ks + 1, cur ^ 1);
    const bf16* Bsc = (const bf16*)(smem + 4096 + (cur << 14));
    bf16x8 af[2], bfr[4];
#pragma unroll
    for (int i = 0; i < 2; ++i) af[i]  = *(const bf16x8*)&XI[(i * 16 + l15) * 264 + ks * 32 + q * 8];
#pragma unroll
    for (int j = 0; j < 4; ++j) bfr[j] = *(const bf16x8*)&Bsc[(w * 64 + j * 16 + l15) * 32 + q * 8];
#pragma unroll
    for (int i = 0; i < 2; ++i)
#pragma unroll
      for (int j = 0; j < 4; ++j)
        acc[i][j] = __builtin_amdgcn_mfma_f32_16x16x32_bf16(af[i], bfr[j], acc[i][j], 0, 0, 0);
    __syncthreads();
    cur ^= 1;
  }
  // pre-issue phase-3's first weight stage; hide under epilogue 2
  STAGE_B(W2, 0, 0);
  // epilogue 2: mish + BNf -> XI (overwrite; reads done per last barrier)
#pragma unroll
  for (int i = 0; i < 2; ++i) {
#pragma unroll
    for (int j = 0; j < 4; ++j) {
      int colb = w * 64 + j * 16 + l15;
#pragma unroll
      for (int r = 0; r < 4; ++r) {
        float v = acc[i][j][r];
        float ex = __expf(v);
        float a = 1.f + ex;
        float u = 1.f / (a * a);
        v = v * (1.f - u) / (1.f + u);
        v = v * pb[512 + colb] + pb[768 + colb];
        XI[(i * 16 + q * 4 + r) * 264 + colb] = (bf16)v;
      }
    }
  }
  __syncthreads();                        // XI(Gm) + staged W2(ks=0) ready

  // ================= phase 3: Gm @ W2^T =================
#pragma unroll
  for (int i = 0; i < 2; ++i)
#pragma unroll
    for (int j = 0; j < 4; ++j) acc[i][j] = f32x4{};
  cur = 0;
  for (int ks = 0; ks < 8; ++ks) {
    if (ks < 7) STAGE_B(W2, ks + 1, cur ^ 1);
    const bf16* Bsc = (const bf16*)(smem + 4096 + (cur << 14));
    bf16x8 af[2], bfr[4];
#pragma unroll
    for (int i = 0; i < 2; ++i) af[i]  = *(const bf16x8*)&XI[(i * 16 + l15) * 264 + ks * 32 + q * 8];
#pragma unroll
    for (int j = 0; j < 4; ++j) bfr[j] = *(const bf16x8*)&Bsc[(w * 64 + j * 16 + l15) * 32 + q * 8];
#pragma unroll
    for (int i = 0; i < 2; ++i)
#pragma unroll
      for (int j = 0; j < 4; ++j)
        acc[i][j] = __builtin_amdgcn_mfma_f32_16x16x32_bf16(af[i], bfr[j], acc[i][j], 0, 0, 0);
    __syncthreads();
    cur ^= 1;
  }

  // epilogue 3: + interR (regs), BN2, transposed coalesced fp32 store
  const int rowl_t = tid & 31;
  const int grow_t = r0 + rowl_t;
  const int nn_t = grow_t / 3000;
  const int rr_t = grow_t - nn_t * 3000;
#pragma unroll
  for (int cc = 0; cc < 4; ++cc) {
    __syncthreads();                      // Tt free (staging dead / prev stored)
    if (w == cc) {
#pragma unroll
      for (int i = 0; i < 2; ++i) {
#pragma unroll
        for (int j = 0; j < 4; ++j) {
          int colb = cc * 64 + j * 16 + l15;
#pragma unroll
          for (int r = 0; r < 4; ++r) {
            unsigned pr = irk[(i * 4 + j) * 2 + (r >> 1)];
            unsigned short us = (r & 1) ? (unsigned short)(pr >> 16)
                                        : (unsigned short)(pr & 0xffff);
            float res = (float)__builtin_bit_cast(bf16, us);
            float v = acc[i][j][r] + res;
            v = v * pb[1024 + colb] + pb[1280 + colb];
            Tt[(i * 16 + q * 4 + r) * 65 + j * 16 + l15] = v;
          }
        }
      }
    }
    __syncthreads();
#pragma unroll
    for (int it = 0; it < 8; ++it) {
      int cl = (tid >> 5) + it * 8;
      int colb = cc * 64 + cl;
      Out2[(size_t)(nn_t * 256 + colb) * 3000 + rr_t] = Tt[rowl_t * 65 + cl];
    }
  }
}

// ---------------- Attention v8b: fused pipeline, disjoint Ofl, 5/CU --------
// bi0: grid-slice offset (launched as 3 x 2560-block dispatches for profiling
// visibility; 2560 = exactly 2.0 residency rounds at 5 blocks/CU).
__global__ __launch_bounds__(256, 5) void k_attn(const bf16* __restrict__ Y,
                                                 bf16* __restrict__ om,
                                                 int bi0) {
  __shared__ __align__(16) char smem[26624];       // all DISJOINT:
  bf16* Vts = (bf16*)smem;                         //  V^T [32][136]   8704 B
  float* Ofl = (float*)(smem + 8704);              //  O 128 x 34 f32 17408 B
  float* Rin = (float*)(smem + 26112);             //  1/s, 128 f32     512 B
  const int tid = threadIdx.x;
  const int bi = blockIdx.x + bi0;
  const int h = bi & 7, b = bi >> 3;
  const int n = b / 120, t = b % 120;
  const bf16* Yb = Y + (size_t)(n * 3100 + t * 25) * 768 + h * 96;
  const int w = tid >> 6, lane = tid & 63;
  const int l31 = lane & 31, hi = lane >> 5;

  // ---- V^T stage: wave w covers d = w*8..w*8+7; lane = m (2-way = free) ----
#pragma unroll
  for (int p = 0; p < 2; ++p) {
    int m = p * 64 + lane;
    if (m < 125) {
      int4 v4 = *(const int4*)(Yb + (size_t)m * 768 + 64 + w * 8);
      bf16x8 v8 = __builtin_bit_cast(bf16x8, v4);
#pragma unroll
      for (int jj = 0; jj < 8; ++jj) Vts[(w * 8 + jj) * 136 + m] = v8[jj];
    }
  }
  if (tid < 96) {                       // zero V pad cols m=125..127
    int d = tid / 3, m = 125 + tid % 3;
    Vts[d * 136 + m] = (bf16)0.f;
  }

  // ---- Q fragment + kt=0 K fragment loads issued before the barrier ----
  int qrow = w * 32 + l31; if (qrow > 124) qrow = 124;
  const bf16* qp = Yb + (size_t)qrow * 768 + hi * 8;
  bf16x8 qf0 = *(const bf16x8*)qp;
  bf16x8 qf1 = *(const bf16x8*)(qp + 16);
  int krow0 = l31; if (krow0 > 124) krow0 = 124;   // kt=0
  const bf16* kp0 = Yb + (size_t)krow0 * 768 + 32 + hi * 8;
  bf16x8 kf0 = *(const bf16x8*)kp0;
  bf16x8 kf1 = *(const bf16x8*)(kp0 + 16);

  __syncthreads();                      // barrier 1: Vts ready

  // ---- fused per-kt: QK-MFMA -> exp2 -> pack -> 2 PV-MFMAs ----
  f32x16 oacc0 = {}, oacc1 = {};
  float s = 0.f;
#pragma unroll
  for (int kt = 0; kt < 4; ++kt) {
    f32x16 acc = {};
    acc = __builtin_amdgcn_mfma_f32_32x32x16_bf16(kf0, qf0, acc, 0, 0, 0);
    acc = __builtin_amdgcn_mfma_f32_32x32x16_bf16(kf1, qf1, acc, 0, 0, 0);
    if (kt < 3) {                       // pipeline next kt's K fragments
      int krow = (kt + 1) * 32 + l31; if (krow > 124) krow = 124;
      const bf16* kp = Yb + (size_t)krow * 768 + 32 + hi * 8;
      kf0 = *(const bf16x8*)kp;
      kf1 = *(const bf16x8*)(kp + 16);
    }
    float e[16];
#pragma unroll
    for (int r = 0; r < 16; ++r) {
      float pz = exp2f(acc[r]);
      if (kt == 3 && r >= 13 && hi) pz = 0.f;
      e[r] = pz;
    }
    float t0 = (e[0] + e[1]) + (e[2] + e[3]);
    float t1 = (e[4] + e[5]) + (e[6] + e[7]);
    float t2 = (e[8] + e[9]) + (e[10] + e[11]);
    float t3 = (e[12] + e[13]) + (e[14] + e[15]);
    s += (t0 + t1) + (t2 + t3);
#pragma unroll
    for (int half = 0; half < 2; ++half) {
      const int ba = half * 8;
      unsigned a0 = cvt_pk_bf16(e[ba + 0], e[ba + 1]);
      unsigned a1 = cvt_pk_bf16(e[ba + 2], e[ba + 3]);
      unsigned b0 = cvt_pk_bf16(e[ba + 4], e[ba + 5]);
      unsigned b1 = cvt_pk_bf16(e[ba + 6], e[ba + 7]);
      pl32_swap(a0, b0);                // fills j0..1 (all lanes) / j4..5
      pl32_swap(a1, b1);                // fills j2..3 / j6..7
      uint32x4 pwv;
      pwv[0] = a0; pwv[1] = a1; pwv[2] = b0; pwv[3] = b1;
      bf16x8 pa = __builtin_bit_cast(bf16x8, pwv);
      const int kc = kt * 2 + half;
      bf16x8 vf = *(const bf16x8*)&Vts[l31 * 136 + kc * 16 + hi * 8];
      if (kc & 1) oacc1 = __builtin_amdgcn_mfma_f32_32x32x16_bf16(pa, vf, oacc1, 0, 0, 0);
      else        oacc0 = __builtin_amdgcn_mfma_f32_32x32x16_bf16(pa, vf, oacc0, 0, 0, 0);
    }
  }
  s += __shfl_xor(s, 32, 64);
  float rinv = 1.f / s;
  if (hi == 0) Rin[w * 32 + l31] = rinv;  // disjoint region, no barrier needed

  // O[query = w*32 + rowmap(r,hi)][d = l31]  (unnormalized; Ofl disjoint)
#pragma unroll
  for (int r = 0; r < 16; ++r) {
    int row = w * 32 + (r & 3) + 8 * (r >> 2) + 4 * hi;
    Ofl[row * 34 + l31] = oacc0[r] + oacc1[r];
  }
  __syncthreads();                      // barrier 2: Ofl/Rin ready
  // mean over W (5 rows), normalize per query via Rin -> om, already /5
  bf16* dst = om + (size_t)((n * 120 + t) * 25) * 256 + h * 32;
  for (int j = tid; j < 800; j += 256) {
    int vv = j >> 5, d = j & 31;
    float s5 = 0.f;
#pragma unroll
    for (int ww = 0; ww < 5; ++ww)
      s5 += Ofl[(ww * 25 + vv) * 34 + d] * Rin[ww * 25 + vv];
    dst[vv * 256 + d] = (bf16)(s5 * 0.2f);
  }
}

// ---------------- launch ----------------
extern "C" void kernel_launch(void* const* d_in, const int* in_sizes, int n_in,
                              void* d_out, int out_size, void* d_ws, size_t ws_size,
                              hipStream_t stream) {
  const size_t NEED1 = 51584000;             // 6-kernel fallback path
  const size_t NEED2 = 63872000;             // fused path: + om2 (12,288,000)
  if (ws_size < NEED1) {
    k_zero<<<(out_size + 255) / 256, 256, 0, stream>>>((float*)d_out, out_size);
    return;
  }
  const float* x     = (const float*)d_in[0];
  const float* wqkv  = (const float*)d_in[1];
  const float* wout  = (const float*)d_in[2];
  const float* b_out = (const float*)d_in[3];
  const float* bn1_g = (const float*)d_in[4];
  const float* bn1_b = (const float*)d_in[5];
  const float* ffn_w1= (const float*)d_in[6];
  const float* ffn_w2= (const float*)d_in[7];
  const float* ffn_g = (const float*)d_in[8];
  const float* ffn_b = (const float*)d_in[9];
  const float* bn2_g = (const float*)d_in[10];
  const float* bn2_b = (const float*)d_in[11];
  const float* bn1_m = (const float*)d_in[12];
  const float* bn1_v = (const float*)d_in[13];
  const float* ffn_m = (const float*)d_in[14];
  const float* ffn_v = (const float*)d_in[15];
  const float* bn2_m = (const float*)d_in[16];
  const float* bn2_v = (const float*)d_in[17];

  char* ws = (char*)d_ws;
  float* pb    = (float*)(ws + 0);           // 7,168
  bf16* WqT    = (bf16*)(ws + 7168);         // 393,216
  bf16* WoT    = (bf16*)(ws + 400384);       // 131,072
  bf16* W1c    = (bf16*)(ws + 531456);       // 131,072
  bf16* W2c    = (bf16*)(ws + 662528);       // 131,072
  bf16* Xrow   = (bf16*)(ws + 793600);       // 12,697,600
  bf16* Y      = (bf16*)(ws + 13491200);     // 38,092,800 -> 51,584,000
  bf16* interR = Y;                          // alias: Y dead after attention
  bf16* Gm     = (bf16*)(ws + 25779200);     // inside Y, disjoint from interR
  bf16* om2    = (bf16*)(ws + 51584000);     // fused path om (12,288,000)
  bf16* om     = (bf16*)d_out;               // fallback path om

  k_prep<<<3141, 256, 0, stream>>>(x, wqkv, wout, b_out, ffn_w1, ffn_w2,
                                   bn1_g, bn1_b, bn1_m, bn1_v,
                                   ffn_g, ffn_b, ffn_m, ffn_v,
                                   bn2_g, bn2_b, bn2_m, bn2_v,
                                   Xrow, WqT, WoT, W1c, W2c, pb);
  k_gemm<0><<<dim3(194, 6), 256, 0, stream>>>(Xrow, WqT, Y, 768, 24800, pb, nullptr, nullptr);
  if (ws_size >= NEED2) {
    k_attn<<<2560, 256, 0, stream>>>(Y, om2, 0);
    k_attn<<<2560, 256, 0, stream>>>(Y, om2, 2560);
    k_attn<<<2560, 256, 0, stream>>>(Y, om2, 5120);
    k_ffn<<<750, 256, 0, stream>>>(om2, WoT, W1c, W2c, Xrow, pb, (float*)d_out);
  } else {
    k_attn<<<7680, 256, 0, stream>>>(Y, om, 0);
    k_gemm<1><<<dim3(188, 2), 256, 0, stream>>>(om, WoT, interR, 256, 24000, pb, Xrow, nullptr);
    k_gemm<2><<<dim3(188, 2), 256, 0, stream>>>(interR, W1c, Gm, 256, 24000, pb, nullptr, nullptr);
    k_gemm<3><<<dim3(188, 2), 256, 0, stream>>>(Gm, W2c, nullptr, 256, 24000, pb, interR, (float*)d_out);
  }
}

// Round 13
// 201.361 us; speedup vs baseline: 1.0572x; 1.0572x over previous
//
#include <hip/hip_runtime.h>
#include <hip/hip_bf16.h>

// SpatioTemporalLayer: N=8,C=256,T=120,V=25,W=5,PAD=2,H=8,CO=256,HD=32,L=125
// Round 23: consolidate after R22's diagnosis (41.8us harness fill + resets
//   are INSIDE the measured loop = fixed overhead; our non-attn kernels are
//   all < 42us). Revert the 3-way attn split (cost ~7us). Two levers:
//   - k_attn: T5 s_setprio(1) around MFMA clusters (independent-block attn =
//     the setprio-positive regime, m191 +4-7%).
//   - k_gemm: (256,3)->(256,4): 16 waves/CU; unified need ~121 <= cap 128.
//  P : k_prep | G1: k_gemm<0> (XCD-swizzled) | A : k_attn | F : k_ffn

using bf16  = __bf16;
using bf16x8 = __bf16 __attribute__((ext_vector_type(8)));
using f32x4  = float __attribute__((ext_vector_type(4)));
using f32x16 = float __attribute__((ext_vector_type(16)));
using uint32x4 = unsigned int __attribute__((ext_vector_type(4)));

#define GAS __attribute__((address_space(1)))
#define LAS __attribute__((address_space(3)))

__device__ __forceinline__ void gload_lds16(const void* g, void* l) {
  __builtin_amdgcn_global_load_lds((GAS void*)g, (LAS void*)l, 16, 0, 0);
}

__device__ __forceinline__ unsigned cvt_pk_bf16(float lo, float hi) {
  unsigned r;
  asm("v_cvt_pk_bf16_f32 %0, %1, %2" : "=v"(r) : "v"(lo), "v"(hi));
  return r;
}

__device__ __forceinline__ void pl32_swap(unsigned& a, unsigned& b) {
  asm("v_permlane32_swap_b32 %0, %1" : "+v"(a), "+v"(b));
}

// ---------------- diagnostic fallback ----------------
__global__ void k_zero(float* out, int n) {
  int i = blockIdx.x * 256 + threadIdx.x;
  if (i < n) out[i] = 0.f;
}

// ---------------- P: merged prep (x-transpose | weights | pad zero) --------
__global__ void k_prep(const float* __restrict__ x,
                       const float* __restrict__ wqkv, const float* __restrict__ wout,
                       const float* __restrict__ b_out,
                       const float* __restrict__ w1, const float* __restrict__ w2,
                       const float* __restrict__ g1, const float* __restrict__ b1,
                       const float* __restrict__ m1, const float* __restrict__ v1,
                       const float* __restrict__ gf, const float* __restrict__ bff,
                       const float* __restrict__ mf, const float* __restrict__ vf,
                       const float* __restrict__ g2, const float* __restrict__ b2,
                       const float* __restrict__ m2, const float* __restrict__ v2,
                       bf16* __restrict__ Xrow, bf16* __restrict__ WqT,
                       bf16* __restrict__ WoT, bf16* __restrict__ W1c,
                       bf16* __restrict__ W2c, float* __restrict__ pb) {
  __shared__ bf16 T[64 * 72];              // pitch 72 breaks transpose conflicts
  const int b = blockIdx.x, tid = threadIdx.x;
  if (b < 1504) {                          // ---- x transpose tile ----
    const int bx = b % 47, by = (b / 47) & 3, n = b / 188;
    const int tv0 = bx * 64, c0 = by * 64;
    const int la = tid & 63, sub = tid >> 6;
#pragma unroll 4
    for (int i = 0; i < 16; ++i) {
      int c = c0 + sub + i * 4;
      int tv = tv0 + la;
      float v = (tv < 3000) ? x[(size_t)(n * 256 + c) * 3000 + tv] : 0.f;
      T[(sub + i * 4) * 72 + la] = (bf16)v;
    }
    __syncthreads();
#pragma unroll 4
    for (int i = 0; i < 16; ++i) {
      int tvl = sub + i * 4;
      int tv = tv0 + tvl;
      if (tv < 3000)
        Xrow[(size_t)(n * 3100 + 50 + tv) * 256 + c0 + la] = T[la * 72 + tvl];
    }
  } else if (b < 3041) {                   // ---- weights + BN params ----
    int idx = (b - 1504) * 256 + tid;
    if (idx < 196608) {
      int c = idx / 768, o = idx % 768;
      float vv = wqkv[idx];
      if ((o % 96) < 32) vv *= 0.0901387929f;   // fold (1/16)*log2e into Wq
      WqT[o * 256 + c] = (bf16)vv;
    } else if (idx < 262144) {
      int j = idx - 196608;
      int c = j >> 8, o = j & 255;
      WoT[o * 256 + c] = (bf16)wout[j];
    } else if (idx < 327680) {
      int j = idx - 262144;
      W1c[j] = (bf16)w1[j];
    } else if (idx < 393216) {
      int j = idx - 327680;
      W2c[j] = (bf16)w2[j];
    } else if (idx < 393472) {
      int k = idx - 393216;
      float s1 = g1[k] * rsqrtf(v1[k] + 1e-5f);
      pb[k]        = s1;
      pb[256 + k]  = b1[k] - m1[k] * s1;
      float sf = gf[k] * rsqrtf(vf[k] + 1e-5f);
      pb[512 + k]  = sf;
      pb[768 + k]  = bff[k] - mf[k] * sf;
      float s2 = g2[k] * rsqrtf(v2[k] + 1e-5f);
      pb[1024 + k] = s2;
      pb[1280 + k] = b2[k] - m2[k] * s2;
      pb[1536 + k] = b_out[k];
    }
  } else {                                 // ---- zero t-pad rows of Xrow ----
    int z = b - 3041;                      // 0..99
    int idx16 = z * 256 + tid;             // each writes 8 bf16 (16 B)
    int e0 = idx16 * 8;
    int pr = e0 >> 8, col = e0 & 255;      // pad row 0..799
    int n = pr / 100, r100 = pr % 100;
    int row = n * 3100 + (r100 < 50 ? r100 : 3000 + r100);
    int4 zz = {};
    *(int4*)&Xrow[(size_t)row * 256 + col] = zz;
  }
}

// ---------------- GEMM (2-phase dbuf, global_load_lds w16, 4/CU) ----------
// EPI==0 applies the bijective XCD swizzle (nwg=1164 -> q=145, r=4).
template <int EPI>
__global__ __launch_bounds__(256, 4) void k_gemm(
    const bf16* __restrict__ A, const bf16* __restrict__ BT,
    bf16* __restrict__ Cout, int ldc, int Mreal,
    const float* __restrict__ pb, const bf16* __restrict__ Res,
    float* __restrict__ Out2) {
  __shared__ __align__(16) char smem[32768];   // 2 x (As 8K | Bs 8K); Tt overlay
  const int tid = threadIdx.x;
  const int w = tid >> 6, lane = tid & 63, q = lane >> 4, l15 = lane & 15;
  int bx = blockIdx.x, by = blockIdx.y;
  if constexpr (EPI == 0) {
    int orig = bx + by * 194;              // gridDim = (194, 6), x-fastest
    int xcd = orig & 7, j = orig >> 3;     // round-robin XCD assignment
    int swz = (xcd < 4) ? xcd * 146 + j : 584 + (xcd - 4) * 145 + j;
    bx = swz / 6; by = swz % 6;            // contiguous m-chunk per XCD
  }
  const int m0 = bx * 128, n0 = by * 128;
  const int wm = (w >> 1) * 64, wn = (w & 1) * 64;
  const int srow = tid >> 2;            // 0..63
  const int scol = (tid & 3) << 3;
  int ar1 = m0 + srow;        if (ar1 >= Mreal) ar1 = Mreal - 1;
  int ar2 = m0 + srow + 64;   if (ar2 >= Mreal) ar2 = Mreal - 1;
  const bf16* gA1 = A  + (size_t)ar1 * 256 + scol;
  const bf16* gA2 = A  + (size_t)ar2 * 256 + scol;
  const bf16* gB1 = BT + (size_t)(n0 + srow) * 256 + scol;
  const bf16* gB2 = gB1 + 64 * 256;
  f32x4 acc[4][4] = {};

  auto STAGE = [&](int ks, char* buf) {
    char* ldsA = buf + w * 1024;          // lane-linear dest per wave
    char* ldsB = buf + 8192 + w * 1024;
    gload_lds16(gA1 + ks * 32, ldsA);
    gload_lds16(gA2 + ks * 32, ldsA + 4096);
    gload_lds16(gB1 + ks * 32, ldsB);
    gload_lds16(gB2 + ks * 32, ldsB + 4096);
  };

  int cur = 0;
  STAGE(0, smem);
  __syncthreads();
  for (int ks = 0; ks < 8; ++ks) {
    if (ks < 7) STAGE(ks + 1, smem + ((cur ^ 1) << 14));
    const bf16* Asc = (const bf16*)(smem + (cur << 14));
    const bf16* Bsc = Asc + 4096;         // +8192 bytes
    bf16x8 af[4], bfr[4];
#pragma unroll
    for (int i = 0; i < 4; ++i) af[i]  = *(const bf16x8*)&Asc[(wm + i * 16 + l15) * 32 + q * 8];
#pragma unroll
    for (int i = 0; i < 4; ++i) bfr[i] = *(const bf16x8*)&Bsc[(wn + i * 16 + l15) * 32 + q * 8];
#pragma unroll
    for (int i = 0; i < 4; ++i)
#pragma unroll
      for (int j = 0; j < 4; ++j)
        acc[i][j] = __builtin_amdgcn_mfma_f32_16x16x32_bf16(af[i], bfr[j], acc[i][j], 0, 0, 0);
    __syncthreads();
    cur ^= 1;
  }

  if constexpr (EPI != 3) {
#pragma unroll
    for (int i = 0; i < 4; ++i) {
#pragma unroll
      for (int j = 0; j < 4; ++j) {
#pragma unroll
        for (int r = 0; r < 4; ++r) {
          int row = m0 + wm + i * 16 + q * 4 + r;
          int col = n0 + wn + j * 16 + l15;
          if (row >= Mreal) continue;
          float v = acc[i][j][r];
          if constexpr (EPI == 0) {
            Cout[(size_t)row * ldc + col] = (bf16)v;
          } else if constexpr (EPI == 1) {
            v += pb[1536 + col];                       // b_out
            int n = row / 3000;                       // x residual at Xrow row+n*100+50
            v += (float)Res[(size_t)(row + n * 100 + 50) * 256 + col];
            v = v * pb[col] + pb[256 + col];          // BN1
            Cout[(size_t)row * 256 + col] = (bf16)v;
          } else {                                    // EPI == 2
            float ex = __expf(v);                     // mish
            float a = 1.f + ex;
            float u = 1.f / (a * a);
            v = v * (1.f - u) / (1.f + u);
            v = v * pb[512 + col] + pb[768 + col];    // BN ffn
            Cout[(size_t)row * 256 + col] = (bf16)v;
          }
        }
      }
    }
  } else {
    // EPI3: +interR residual, BN2, LDS-transposed coalesced fp32 store
    float* Tt = (float*)smem;              // 2 tiles of 128 x pitch-19 fp32
    const int tti = (w & 1);               // wave's col-half
#pragma unroll
    for (int jj = 0; jj < 4; ++jj) {
      __syncthreads();                     // previous phase's Tt reads done
#pragma unroll
      for (int i = 0; i < 4; ++i) {
#pragma unroll
        for (int r = 0; r < 4; ++r) {
          int rowl = wm + i * 16 + q * 4 + r;
          int row = m0 + rowl;
          int col = n0 + tti * 64 + jj * 16 + l15;
          float v = acc[i][jj][r];
          v += (float)Res[(size_t)row * 256 + col];   // + interR (in-bounds alloc)
          v = v * pb[1024 + col] + pb[1280 + col];    // BN2
          Tt[tti * 2432 + rowl * 19 + l15] = v;
        }
      }
      __syncthreads();
#pragma unroll
      for (int k = 0; k < 16; ++k) {
        int flat = k * 256 + tid;          // 4096 values
        int tt2 = flat >> 11;
        int rem = flat & 2047;
        int colL = rem >> 7;
        int rowl = rem & 127;
        int row = m0 + rowl;
        if (row < Mreal) {
          int col = n0 + tt2 * 64 + jj * 16 + colL;
          int n = row / 3000, r2 = row - n * 3000;
          Out2[(size_t)(n * 256 + col) * 3000 + r2] = Tt[tt2 * 2432 + rowl * 19 + colL];
        }
      }
    }
  }
}

// ---------------- F: fused FFN chain (G2+G3+G4), 32-row tiles, 3/CU -------
__global__ __launch_bounds__(256, 3) void k_ffn(
    const bf16* __restrict__ Aom, const bf16* __restrict__ Wo,
    const bf16* __restrict__ W1, const bf16* __restrict__ W2,
    const bf16* __restrict__ Xres, const float* __restrict__ pb,
    float* __restrict__ Out2) {
  __shared__ __align__(16) char smem[53760];
  // As dbuf [2][32][32] @ 0,2048 ; Bs dbuf [2][256][32] @ 4096,20480
  // XI [32][264] @ 36864 ; Tt overlay [32][65] f32 @ 0
  bf16* XI = (bf16*)(smem + 36864);
  float* Tt = (float*)smem;
  const int tid = threadIdx.x;
  const int w = tid >> 6, lane = tid & 63, q = lane >> 4, l15 = lane & 15;
  const int r0 = blockIdx.x * 32;
  const int srow = tid >> 2, scol = (tid & 3) << 3;

  auto STAGE_A = [&](int ks, int b) {
    if (w == 0) {                          // 2 KB: wave 0 issues 2 gloads
      char* ldsA = smem + (b << 11);
      const bf16* src = Aom + (size_t)(r0 + (lane >> 2)) * 256 + ks * 32 + ((lane & 3) << 3);
      gload_lds16(src, ldsA);              // rows 0..15
      gload_lds16(src + 16 * 256, ldsA + 1024);  // rows 16..31
    }
  };
  auto STAGE_B = [&](const bf16* Wsrc, int ks, int b) {
    char* ldsB = smem + 4096 + (b << 14) + w * 1024;
#pragma unroll
    for (int ii = 0; ii < 4; ++ii)
      gload_lds16(Wsrc + (size_t)(ii * 64 + srow) * 256 + ks * 32 + scol,
                  ldsB + ii * 4096);
  };

  f32x4 acc[2][4];
#pragma unroll
  for (int i = 0; i < 2; ++i)
#pragma unroll
    for (int j = 0; j < 4; ++j) acc[i][j] = f32x4{};

  // ================= phase 1: om @ Wo =================
  int cur = 0;
  STAGE_A(0, 0); STAGE_B(Wo, 0, 0);
  __syncthreads();
  for (int ks = 0; ks < 8; ++ks) {
    if (ks < 7) { STAGE_A(ks + 1, cur ^ 1); STAGE_B(Wo, ks + 1, cur ^ 1); }
    const bf16* Asc = (const bf16*)(smem + (cur << 11));
    const bf16* Bsc = (const bf16*)(smem + 4096 + (cur << 14));
    bf16x8 af[2], bfr[4];
#pragma unroll
    for (int i = 0; i < 2; ++i) af[i]  = *(const bf16x8*)&Asc[(i * 16 + l15) * 32 + q * 8];
#pragma unroll
    for (int j = 0; j < 4; ++j) bfr[j] = *(const bf16x8*)&Bsc[(w * 64 + j * 16 + l15) * 32 + q * 8];
#pragma unroll
    for (int i = 0; i < 2; ++i)
#pragma unroll
      for (int j = 0; j < 4; ++j)
        acc[i][j] = __builtin_amdgcn_mfma_f32_16x16x32_bf16(af[i], bfr[j], acc[i][j], 0, 0, 0);
    __syncthreads();
    cur ^= 1;
  }
  // pre-issue phase-2's first weight stage; hide under epilogue 1
  STAGE_B(W1, 0, 0);
  // epilogue 1: +b_out, +x residual, BN1 -> XI (LDS) + irk (packed regs)
  unsigned irk[16];
#pragma unroll
  for (int i = 0; i < 2; ++i) {
#pragma unroll
    for (int j = 0; j < 4; ++j) {
      int colb = w * 64 + j * 16 + l15;
      float vv[4];
#pragma unroll
      for (int r = 0; r < 4; ++r) {
        int grow = r0 + i * 16 + q * 4 + r;
        int nn = grow / 3000;
        float v = acc[i][j][r] + pb[1536 + colb]
                + (float)Xres[(size_t)(grow + nn * 100 + 50) * 256 + colb];
        v = v * pb[colb] + pb[256 + colb];
        vv[r] = v;
        XI[(i * 16 + q * 4 + r) * 264 + colb] = (bf16)v;
      }
      irk[(i * 4 + j) * 2 + 0] = cvt_pk_bf16(vv[0], vv[1]);
      irk[(i * 4 + j) * 2 + 1] = cvt_pk_bf16(vv[2], vv[3]);
    }
  }
  __syncthreads();                        // XI + staged W1(ks=0) ready

  // ================= phase 2: interR @ W1^T, mish, BNf =================
#pragma unroll
  for (int i = 0; i < 2; ++i)
#pragma unroll
    for (int j = 0; j < 4; ++j) acc[i][j] = f32x4{};
  cur = 0;
  for (int ks = 0; ks < 8; ++ks) {
    if (ks < 7) STAGE_B(W1, ks + 1, cur ^ 1);
    const bf16* Bsc = (const bf16*)(smem + 4096 + (cur << 14));
    bf16x8 af[2], bfr[4];
#pragma unroll
    for (int i = 0; i < 2; ++i) af[i]  = *(const bf16x8*)&XI[(i * 16 + l15) * 264 + ks * 32 + q * 8];
#pragma unroll
    for (int j = 0; j < 4; ++j) bfr[j] = *(const bf16x8*)&Bsc[(w * 64 + j * 16 + l15) * 32 + q * 8];
#pragma unroll
    for (int i = 0; i < 2; ++i)
#pragma unroll
      for (int j = 0; j < 4; ++j)
        acc[i][j] = __builtin_amdgcn_mfma_f32_16x16x32_bf16(af[i], bfr[j], acc[i][j], 0, 0, 0);
    __syncthreads();
    cur ^= 1;
  }
  // pre-issue phase-3's first weight stage; hide under epilogue 2
  STAGE_B(W2, 0, 0);
  // epilogue 2: mish + BNf -> XI (overwrite; reads done per last barrier)
#pragma unroll
  for (int i = 0; i < 2; ++i) {
#pragma unroll
    for (int j = 0; j < 4; ++j) {
      int colb = w * 64 + j * 16 + l15;
#pragma unroll
      for (int r = 0; r < 4; ++r) {
        float v = acc[i][j][r];
        float ex = __expf(v);
        float a = 1.f + ex;
        float u = 1.f / (a * a);
        v = v * (1.f - u) / (1.f + u);
        v = v * pb[512 + colb] + pb[768 + colb];
        XI[(i * 16 + q * 4 + r) * 264 + colb] = (bf16)v;
      }
    }
  }
  __syncthreads();                        // XI(Gm) + staged W2(ks=0) ready

  // ================= phase 3: Gm @ W2^T =================
#pragma unroll
  for (int i = 0; i < 2; ++i)
#pragma unroll
    for (int j = 0; j < 4; ++j) acc[i][j] = f32x4{};
  cur = 0;
  for (int ks = 0; ks < 8; ++ks) {
    if (ks < 7) STAGE_B(W2, ks + 1, cur ^ 1);
    const bf16* Bsc = (const bf16*)(smem + 4096 + (cur << 14));
    bf16x8 af[2], bfr[4];
#pragma unroll
    for (int i = 0; i < 2; ++i) af[i]  = *(const bf16x8*)&XI[(i * 16 + l15) * 264 + ks * 32 + q * 8];
#pragma unroll
    for (int j = 0; j < 4; ++j) bfr[j] = *(const bf16x8*)&Bsc[(w * 64 + j * 16 + l15) * 32 + q * 8];
#pragma unroll
    for (int i = 0; i < 2; ++i)
#pragma unroll
      for (int j = 0; j < 4; ++j)
        acc[i][j] = __builtin_amdgcn_mfma_f32_16x16x32_bf16(af[i], bfr[j], acc[i][j], 0, 0, 0);
    __syncthreads();
    cur ^= 1;
  }

  // epilogue 3: + interR (regs), BN2, transposed coalesced fp32 store
  const int rowl_t = tid & 31;
  const int grow_t = r0 + rowl_t;
  const int nn_t = grow_t / 3000;
  const int rr_t = grow_t - nn_t * 3000;
#pragma unroll
  for (int cc = 0; cc < 4; ++cc) {
    __syncthreads();                      // Tt free (staging dead / prev stored)
    if (w == cc) {
#pragma unroll
      for (int i = 0; i < 2; ++i) {
#pragma unroll
        for (int j = 0; j < 4; ++j) {
          int colb = cc * 64 + j * 16 + l15;
#pragma unroll
          for (int r = 0; r < 4; ++r) {
            unsigned pr = irk[(i * 4 + j) * 2 + (r >> 1)];
            unsigned short us = (r & 1) ? (unsigned short)(pr >> 16)
                                        : (unsigned short)(pr & 0xffff);
            float res = (float)__builtin_bit_cast(bf16, us);
            float v = acc[i][j][r] + res;
            v = v * pb[1024 + colb] + pb[1280 + colb];
            Tt[(i * 16 + q * 4 + r) * 65 + j * 16 + l15] = v;
          }
        }
      }
    }
    __syncthreads();
#pragma unroll
    for (int it = 0; it < 8; ++it) {
      int cl = (tid >> 5) + it * 8;
      int colb = cc * 64 + cl;
      Out2[(size_t)(nn_t * 256 + colb) * 3000 + rr_t] = Tt[rowl_t * 65 + cl];
    }
  }
}

// ---------------- Attention v9: v8b + T5 setprio around MFMA clusters ------
__global__ __launch_bounds__(256, 5) void k_attn(const bf16* __restrict__ Y,
                                                 bf16* __restrict__ om) {
  __shared__ __align__(16) char smem[26624];       // all DISJOINT:
  bf16* Vts = (bf16*)smem;                         //  V^T [32][136]   8704 B
  float* Ofl = (float*)(smem + 8704);              //  O 128 x 34 f32 17408 B
  float* Rin = (float*)(smem + 26112);             //  1/s, 128 f32     512 B
  const int tid = threadIdx.x;
  const int bi = blockIdx.x;
  const int h = bi & 7, b = bi >> 3;
  const int n = b / 120, t = b % 120;
  const bf16* Yb = Y + (size_t)(n * 3100 + t * 25) * 768 + h * 96;
  const int w = tid >> 6, lane = tid & 63;
  const int l31 = lane & 31, hi = lane >> 5;

  // ---- V^T stage: wave w covers d = w*8..w*8+7; lane = m (2-way = free) ----
#pragma unroll
  for (int p = 0; p < 2; ++p) {
    int m = p * 64 + lane;
    if (m < 125) {
      int4 v4 = *(const int4*)(Yb + (size_t)m * 768 + 64 + w * 8);
      bf16x8 v8 = __builtin_bit_cast(bf16x8, v4);
#pragma unroll
      for (int jj = 0; jj < 8; ++jj) Vts[(w * 8 + jj) * 136 + m] = v8[jj];
    }
  }
  if (tid < 96) {                       // zero V pad cols m=125..127
    int d = tid / 3, m = 125 + tid % 3;
    Vts[d * 136 + m] = (bf16)0.f;
  }

  // ---- Q fragment + kt=0 K fragment loads issued before the barrier ----
  int qrow = w * 32 + l31; if (qrow > 124) qrow = 124;
  const bf16* qp = Yb + (size_t)qrow * 768 + hi * 8;
  bf16x8 qf0 = *(const bf16x8*)qp;
  bf16x8 qf1 = *(const bf16x8*)(qp + 16);
  int krow0 = l31; if (krow0 > 124) krow0 = 124;   // kt=0
  const bf16* kp0 = Yb + (size_t)krow0 * 768 + 32 + hi * 8;
  bf16x8 kf0 = *(const bf16x8*)kp0;
  bf16x8 kf1 = *(const bf16x8*)(kp0 + 16);

  __syncthreads();                      // barrier 1: Vts ready

  // ---- fused per-kt: QK-MFMA -> exp2 -> pack -> 2 PV-MFMAs ----
  f32x16 oacc0 = {}, oacc1 = {};
  float s = 0.f;
#pragma unroll
  for (int kt = 0; kt < 4; ++kt) {
    f32x16 acc = {};
    __builtin_amdgcn_s_setprio(1);
    acc = __builtin_amdgcn_mfma_f32_32x32x16_bf16(kf0, qf0, acc, 0, 0, 0);
    acc = __builtin_amdgcn_mfma_f32_32x32x16_bf16(kf1, qf1, acc, 0, 0, 0);
    __builtin_amdgcn_s_setprio(0);
    if (kt < 3) {                       // pipeline next kt's K fragments
      int krow = (kt + 1) * 32 + l31; if (krow > 124) krow = 124;
      const bf16* kp = Yb + (size_t)krow * 768 + 32 + hi * 8;
      kf0 = *(const bf16x8*)kp;
      kf1 = *(const bf16x8*)(kp + 16);
    }
    float e[16];
#pragma unroll
    for (int r = 0; r < 16; ++r) {
      float pz = exp2f(acc[r]);
      if (kt == 3 && r >= 13 && hi) pz = 0.f;
      e[r] = pz;
    }
    float t0 = (e[0] + e[1]) + (e[2] + e[3]);
    float t1 = (e[4] + e[5]) + (e[6] + e[7]);
    float t2 = (e[8] + e[9]) + (e[10] + e[11]);
    float t3 = (e[12] + e[13]) + (e[14] + e[15]);
    s += (t0 + t1) + (t2 + t3);
#pragma unroll
    for (int half = 0; half < 2; ++half) {
      const int ba = half * 8;
      unsigned a0 = cvt_pk_bf16(e[ba + 0], e[ba + 1]);
      unsigned a1 = cvt_pk_bf16(e[ba + 2], e[ba + 3]);
      unsigned b0 = cvt_pk_bf16(e[ba + 4], e[ba + 5]);
      unsigned b1 = cvt_pk_bf16(e[ba + 6], e[ba + 7]);
      pl32_swap(a0, b0);                // fills j0..1 (all lanes) / j4..5
      pl32_swap(a1, b1);                // fills j2..3 / j6..7
      uint32x4 pwv;
      pwv[0] = a0; pwv[1] = a1; pwv[2] = b0; pwv[3] = b1;
      bf16x8 pa = __builtin_bit_cast(bf16x8, pwv);
      const int kc = kt * 2 + half;
      bf16x8 vf = *(const bf16x8*)&Vts[l31 * 136 + kc * 16 + hi * 8];
      __builtin_amdgcn_s_setprio(1);
      if (kc & 1) oacc1 = __builtin_amdgcn_mfma_f32_32x32x16_bf16(pa, vf, oacc1, 0, 0, 0);
      else        oacc0 = __builtin_amdgcn_mfma_f32_32x32x16_bf16(pa, vf, oacc0, 0, 0, 0);
      __builtin_amdgcn_s_setprio(0);
    }
  }
  s += __shfl_xor(s, 32, 64);
  float rinv = 1.f / s;
  if (hi == 0) Rin[w * 32 + l31] = rinv;  // disjoint region, no barrier needed

  // O[query = w*32 + rowmap(r,hi)][d = l31]  (unnormalized; Ofl disjoint)
#pragma unroll
  for (int r = 0; r < 16; ++r) {
    int row = w * 32 + (r & 3) + 8 * (r >> 2) + 4 * hi;
    Ofl[row * 34 + l31] = oacc0[r] + oacc1[r];
  }
  __syncthreads();                      // barrier 2: Ofl/Rin ready
  // mean over W (5 rows), normalize per query via Rin -> om, already /5
  bf16* dst = om + (size_t)((n * 120 + t) * 25) * 256 + h * 32;
  for (int j = tid; j < 800; j += 256) {
    int vv = j >> 5, d = j & 31;
    float s5 = 0.f;
#pragma unroll
    for (int ww = 0; ww < 5; ++ww)
      s5 += Ofl[(ww * 25 + vv) * 34 + d] * Rin[ww * 25 + vv];
    dst[vv * 256 + d] = (bf16)(s5 * 0.2f);
  }
}

// ---------------- launch ----------------
extern "C" void kernel_launch(void* const* d_in, const int* in_sizes, int n_in,
                              void* d_out, int out_size, void* d_ws, size_t ws_size,
                              hipStream_t stream) {
  const size_t NEED1 = 51584000;             // 6-kernel fallback path
  const size_t NEED2 = 63872000;             // fused path: + om2 (12,288,000)
  if (ws_size < NEED1) {
    k_zero<<<(out_size + 255) / 256, 256, 0, stream>>>((float*)d_out, out_size);
    return;
  }
  const float* x     = (const float*)d_in[0];
  const float* wqkv  = (const float*)d_in[1];
  const float* wout  = (const float*)d_in[2];
  const float* b_out = (const float*)d_in[3];
  const float* bn1_g = (const float*)d_in[4];
  const float* bn1_b = (const float*)d_in[5];
  const float* ffn_w1= (const float*)d_in[6];
  const float* ffn_w2= (const float*)d_in[7];
  const float* ffn_g = (const float*)d_in[8];
  const float* ffn_b = (const float*)d_in[9];
  const float* bn2_g = (const float*)d_in[10];
  const float* bn2_b = (const float*)d_in[11];
  const float* bn1_m = (const float*)d_in[12];
  const float* bn1_v = (const float*)d_in[13];
  const float* ffn_m = (const float*)d_in[14];
  const float* ffn_v = (const float*)d_in[15];
  const float* bn2_m = (const float*)d_in[16];
  const float* bn2_v = (const float*)d_in[17];

  char* ws = (char*)d_ws;
  float* pb    = (float*)(ws + 0);           // 7,168
  bf16* WqT    = (bf16*)(ws + 7168);         // 393,216
  bf16* WoT    = (bf16*)(ws + 400384);       // 131,072
  bf16* W1c    = (bf16*)(ws + 531456);       // 131,072
  bf16* W2c    = (bf16*)(ws + 662528);       // 131,072
  bf16* Xrow   = (bf16*)(ws + 793600);       // 12,697,600
  bf16* Y      = (bf16*)(ws + 13491200);     // 38,092,800 -> 51,584,000
  bf16* interR = Y;                          // alias: Y dead after attention
  bf16* Gm     = (bf16*)(ws + 25779200);     // inside Y, disjoint from interR
  bf16* om2    = (bf16*)(ws + 51584000);     // fused path om (12,288,000)
  bf16* om     = (bf16*)d_out;               // fallback path om

  k_prep<<<3141, 256, 0, stream>>>(x, wqkv, wout, b_out, ffn_w1, ffn_w2,
                                   bn1_g, bn1_b, bn1_m, bn1_v,
                                   ffn_g, ffn_b, ffn_m, ffn_v,
                                   bn2_g, bn2_b, bn2_m, bn2_v,
                                   Xrow, WqT, WoT, W1c, W2c, pb);
  k_gemm<0><<<dim3(194, 6), 256, 0, stream>>>(Xrow, WqT, Y, 768, 24800, pb, nullptr, nullptr);
  if (ws_size >= NEED2) {
    k_attn<<<7680, 256, 0, stream>>>(Y, om2);
    k_ffn<<<750, 256, 0, stream>>>(om2, WoT, W1c, W2c, Xrow, pb, (float*)d_out);
  } else {
    k_attn<<<7680, 256, 0, stream>>>(Y, om);
    k_gemm<1><<<dim3(188, 2), 256, 0, stream>>>(om, WoT, interR, 256, 24000, pb, Xrow, nullptr);
    k_gemm<2><<<dim3(188, 2), 256, 0, stream>>>(interR, W1c, Gm, 256, 24000, pb, nullptr, nullptr);
    k_gemm<3><<<dim3(188, 2), 256, 0, stream>>>(Gm, W2c, nullptr, 256, 24000, pb, interR, (float*)d_out);
  }
}